// Round 1
// baseline (215.955 us; speedup 1.0000x reference)
//
#include <hip/hip_runtime.h>

// InformPooling: 3-scale segment-mean pooling.
//   value0 [8,16384,128] r=1.0 ; value1 [8,8192,128] r=0.5 ; value2 [8,4096,256] r=0.25
//   start/duration [8,512]; out [8,512,512] f32 (channels concat 128|128|256).
// One wave per (b,n,pool): s,e are wave-uniform -> no divergence.
// Pool0/1: lane owns float2 (64*2 = 128 ch/row). Pool2: lane owns float4 (64*4 = 256 ch/row).
// 2 timesteps/iter with dual accumulators for load pipelining.

constexpr int   kB   = 8;
constexpr int   kN   = 512;
constexpr float kEps = 1e-3f;

__global__ __launch_bounds__(256) void inform_pool_kernel(
    const float* __restrict__ v0, const float* __restrict__ v1,
    const float* __restrict__ v2, const float* __restrict__ start,
    const float* __restrict__ dur, float* __restrict__ out)
{
    const int wave = threadIdx.x >> 6;
    const int lane = threadIdx.x & 63;
    const int bn   = blockIdx.x * 4 + wave;   // [0, 4096)
    const int b    = bn >> 9;                 // bn / 512
    const int pool = blockIdx.y;              // 0,1,2

    const float st = start[bn];
    const float du = dur[bn];

    float* outbase = out + (size_t)bn * 512;

    if (pool < 2) {
        const float* v = (pool == 0) ? v0 : v1;
        const int    T = (pool == 0) ? 16384 : 8192;
        const float  r = (pool == 0) ? 1.0f : 0.5f;
        const int s = min((int)floorf(st * r), T - 1);
        const int e = min((int)ceilf((st + du + kEps) * r), T - 1);
        const int cnt = e - s;

        float2 a0 = make_float2(0.f, 0.f);
        float2 a1 = make_float2(0.f, 0.f);
        const float2* p = (const float2*)(v + ((size_t)b * T + s) * 128) + lane;
        int t = s;
        for (; t + 2 <= e; t += 2, p += 128) {   // 128 float2 = 2 rows
            float2 x = p[0];
            float2 y = p[64];
            a0.x += x.x; a0.y += x.y;
            a1.x += y.x; a1.y += y.y;
        }
        if (t < e) {
            float2 x = p[0];
            a0.x += x.x; a0.y += x.y;
        }
        float2 res = make_float2(0.f, 0.f);
        if (cnt > 0) {
            const float c = (float)cnt;
            res.x = (a0.x + a1.x) / c;
            res.y = (a0.y + a1.y) / c;
        }
        ((float2*)(outbase + (pool == 0 ? 0 : 128)))[lane] = res;
    } else {
        const int   T = 4096;
        const float r = 0.25f;
        const int s = min((int)floorf(st * r), T - 1);
        const int e = min((int)ceilf((st + du + kEps) * r), T - 1);
        const int cnt = e - s;

        float4 a0 = make_float4(0.f, 0.f, 0.f, 0.f);
        float4 a1 = make_float4(0.f, 0.f, 0.f, 0.f);
        const float4* p = (const float4*)(v2 + ((size_t)b * T + s) * 256) + lane;
        int t = s;
        for (; t + 2 <= e; t += 2, p += 128) {   // 128 float4 = 2 rows
            float4 x = p[0];
            float4 y = p[64];
            a0.x += x.x; a0.y += x.y; a0.z += x.z; a0.w += x.w;
            a1.x += y.x; a1.y += y.y; a1.z += y.z; a1.w += y.w;
        }
        if (t < e) {
            float4 x = p[0];
            a0.x += x.x; a0.y += x.y; a0.z += x.z; a0.w += x.w;
        }
        float4 res = make_float4(0.f, 0.f, 0.f, 0.f);
        if (cnt > 0) {
            const float c = (float)cnt;
            res.x = (a0.x + a1.x) / c;
            res.y = (a0.y + a1.y) / c;
            res.z = (a0.z + a1.z) / c;
            res.w = (a0.w + a1.w) / c;
        }
        ((float4*)(outbase + 256))[lane] = res;
    }
}

extern "C" void kernel_launch(void* const* d_in, const int* in_sizes, int n_in,
                              void* d_out, int out_size, void* d_ws, size_t ws_size,
                              hipStream_t stream) {
    const float* v0    = (const float*)d_in[0];
    const float* v1    = (const float*)d_in[1];
    const float* v2    = (const float*)d_in[2];
    const float* start = (const float*)d_in[3];
    const float* dur   = (const float*)d_in[4];
    float*       out   = (float*)d_out;

    dim3 grid(kB * kN / 4, 3);   // 4 waves (= 4 bn) per block, pool in y
    inform_pool_kernel<<<grid, 256, 0, stream>>>(v0, v1, v2, start, dur, out);
}

// Round 2
// 171.998 us; speedup vs baseline: 1.2556x; 1.2556x over previous
//
#include <hip/hip_runtime.h>

// InformPooling, two-pass chunk-sum scheme.
//   value0 [8,16384,128] r=1.0 ; value1 [8,8192,128] r=0.5 ; value2 [8,4096,256] r=0.25
//   start/duration [8,512]; out [8,512,512] f32 (channels concat 128|128|256).
//
// Pass 1 (chunk_sum): stream v once, write sums of C=8 consecutive rows into d_ws.
//   S0 [8][2048][128], S1 [8][1024][128], S2 [8][512][256]  -> 16.8 MB total (LLC-hot).
// Pass 2 (gather): per (b,n,pool) wave: interior = ~len/8 chunk-row reads from S,
//   edges = <=7 direct rows from v at each end. Cuts logical read volume ~5x
//   (634 MB -> ~125 MB) vs direct summation (R0: 107 us, 5.9 TB/s logical).

constexpr int   kB   = 8;
constexpr int   kN   = 512;
constexpr float kEps = 1e-3f;
constexpr int   kC   = 8;  // chunk rows

// float offsets into ws
constexpr size_t S0_OFF = 0;                       // 8*2048*128
constexpr size_t S1_OFF = (size_t)8 * 2048 * 128;  // + 8*1024*128
constexpr size_t S2_OFF = S1_OFF + (size_t)8 * 1024 * 128;

__global__ __launch_bounds__(256) void chunk_sum_kernel(
    const float* __restrict__ v0, const float* __restrict__ v1,
    const float* __restrict__ v2, float* __restrict__ ws)
{
    const int w    = (blockIdx.x * 256 + threadIdx.x) >> 6;  // global wave id
    const int lane = threadIdx.x & 63;

    if (w < 16384) {                       // pool0: b*2048 chunks
        const int b = w >> 11, tc = w & 2047;
        const float2* p = (const float2*)(v0 + ((size_t)b * 16384 + (size_t)tc * kC) * 128) + lane;
        float2 a = make_float2(0.f, 0.f);
#pragma unroll
        for (int i = 0; i < kC; i++) { float2 x = p[i * 64]; a.x += x.x; a.y += x.y; }
        ((float2*)(ws + S0_OFF))[(size_t)w * 64 + lane] = a;
    } else if (w < 24576) {                // pool1: b*1024 chunks
        const int idx = w - 16384;
        const int b = idx >> 10, tc = idx & 1023;
        const float2* p = (const float2*)(v1 + ((size_t)b * 8192 + (size_t)tc * kC) * 128) + lane;
        float2 a = make_float2(0.f, 0.f);
#pragma unroll
        for (int i = 0; i < kC; i++) { float2 x = p[i * 64]; a.x += x.x; a.y += x.y; }
        ((float2*)(ws + S1_OFF))[(size_t)idx * 64 + lane] = a;
    } else if (w < 28672) {                // pool2: b*512 chunks, 256 ch
        const int idx = w - 24576;
        const int b = idx >> 9, tc = idx & 511;
        const float4* p = (const float4*)(v2 + ((size_t)b * 4096 + (size_t)tc * kC) * 256) + lane;
        float4 a = make_float4(0.f, 0.f, 0.f, 0.f);
#pragma unroll
        for (int i = 0; i < kC; i++) {
            float4 x = p[i * 64];
            a.x += x.x; a.y += x.y; a.z += x.z; a.w += x.w;
        }
        ((float4*)(ws + S2_OFF))[(size_t)idx * 64 + lane] = a;
    }
}

__global__ __launch_bounds__(256) void gather_kernel(
    const float* __restrict__ v0, const float* __restrict__ v1,
    const float* __restrict__ v2, const float* __restrict__ start,
    const float* __restrict__ dur, const float* __restrict__ ws,
    float* __restrict__ out)
{
    const int wave = threadIdx.x >> 6;
    const int lane = threadIdx.x & 63;
    const int bn   = blockIdx.x * 4 + wave;   // [0, 4096)
    const int b    = bn >> 9;
    const int pool = blockIdx.y;

    const float st = start[bn];
    const float du = dur[bn];
    float* outbase = out + (size_t)bn * 512;

    if (pool < 2) {
        const float*  v   = (pool == 0) ? v0 : v1;
        const float*  S   = ws + ((pool == 0) ? S0_OFF : S1_OFF);
        const int     T   = (pool == 0) ? 16384 : 8192;
        const int     NC  = T / kC;
        const float   r   = (pool == 0) ? 1.0f : 0.5f;
        const int s = min((int)floorf(st * r), T - 1);
        const int e = min((int)ceilf((st + du + kEps) * r), T - 1);
        const int cnt = e - s;

        float2 a0 = make_float2(0.f, 0.f);
        float2 a1 = make_float2(0.f, 0.f);
        if (cnt > 0) {
            const float2* vp = (const float2*)(v + (size_t)b * T * 128) + lane;
            const int cs = (s + kC - 1) >> 3;
            const int ce = e >> 3;
            if (ce > cs) {
                const float2* Sp = (const float2*)(S + (size_t)b * NC * 128) + lane;
                int c = cs;
                for (; c + 2 <= ce; c += 2) {                 // interior, 2 chunks/iter
                    float2 x = Sp[(size_t)c * 64];
                    float2 y = Sp[(size_t)(c + 1) * 64];
                    a0.x += x.x; a0.y += x.y;
                    a1.x += y.x; a1.y += y.y;
                }
                if (c < ce) { float2 x = Sp[(size_t)c * 64]; a0.x += x.x; a0.y += x.y; }
                for (int t = s; t < cs * kC; t++) {            // front edge (<=7)
                    float2 x = vp[(size_t)t * 64]; a0.x += x.x; a0.y += x.y;
                }
                for (int t = ce * kC; t < e; t++) {            // back edge (<=7)
                    float2 x = vp[(size_t)t * 64]; a1.x += x.x; a1.y += x.y;
                }
            } else {
                for (int t = s; t < e; t++) {                  // short segment
                    float2 x = vp[(size_t)t * 64]; a0.x += x.x; a0.y += x.y;
                }
            }
        }
        float2 res = make_float2(0.f, 0.f);
        if (cnt > 0) {
            const float c = (float)cnt;
            res.x = (a0.x + a1.x) / c;
            res.y = (a0.y + a1.y) / c;
        }
        ((float2*)(outbase + (pool == 0 ? 0 : 128)))[lane] = res;
    } else {
        const int   T  = 4096;
        const int   NC = T / kC;
        const float r  = 0.25f;
        const int s = min((int)floorf(st * r), T - 1);
        const int e = min((int)ceilf((st + du + kEps) * r), T - 1);
        const int cnt = e - s;

        float4 a0 = make_float4(0.f, 0.f, 0.f, 0.f);
        float4 a1 = make_float4(0.f, 0.f, 0.f, 0.f);
        if (cnt > 0) {
            const float4* vp = (const float4*)(v2 + (size_t)b * T * 256) + lane;
            const int cs = (s + kC - 1) >> 3;
            const int ce = e >> 3;
            if (ce > cs) {
                const float4* Sp = (const float4*)(ws + S2_OFF + (size_t)b * NC * 256) + lane;
                int c = cs;
                for (; c + 2 <= ce; c += 2) {
                    float4 x = Sp[(size_t)c * 64];
                    float4 y = Sp[(size_t)(c + 1) * 64];
                    a0.x += x.x; a0.y += x.y; a0.z += x.z; a0.w += x.w;
                    a1.x += y.x; a1.y += y.y; a1.z += y.z; a1.w += y.w;
                }
                if (c < ce) {
                    float4 x = Sp[(size_t)c * 64];
                    a0.x += x.x; a0.y += x.y; a0.z += x.z; a0.w += x.w;
                }
                for (int t = s; t < cs * kC; t++) {
                    float4 x = vp[(size_t)t * 64];
                    a0.x += x.x; a0.y += x.y; a0.z += x.z; a0.w += x.w;
                }
                for (int t = ce * kC; t < e; t++) {
                    float4 x = vp[(size_t)t * 64];
                    a1.x += x.x; a1.y += x.y; a1.z += x.z; a1.w += x.w;
                }
            } else {
                for (int t = s; t < e; t++) {
                    float4 x = vp[(size_t)t * 64];
                    a0.x += x.x; a0.y += x.y; a0.z += x.z; a0.w += x.w;
                }
            }
        }
        float4 res = make_float4(0.f, 0.f, 0.f, 0.f);
        if (cnt > 0) {
            const float c = (float)cnt;
            res.x = (a0.x + a1.x) / c;
            res.y = (a0.y + a1.y) / c;
            res.z = (a0.z + a1.z) / c;
            res.w = (a0.w + a1.w) / c;
        }
        ((float4*)(outbase + 256))[lane] = res;
    }
}

extern "C" void kernel_launch(void* const* d_in, const int* in_sizes, int n_in,
                              void* d_out, int out_size, void* d_ws, size_t ws_size,
                              hipStream_t stream) {
    const float* v0    = (const float*)d_in[0];
    const float* v1    = (const float*)d_in[1];
    const float* v2    = (const float*)d_in[2];
    const float* start = (const float*)d_in[3];
    const float* dur   = (const float*)d_in[4];
    float*       out   = (float*)d_out;
    float*       ws    = (float*)d_ws;

    // Pass 1: 28672 waves (16384 + 8192 + 4096), 4 waves/block
    chunk_sum_kernel<<<dim3(28672 / 4), 256, 0, stream>>>(v0, v1, v2, ws);
    // Pass 2: one wave per (bn, pool)
    gather_kernel<<<dim3(kB * kN / 4, 3), 256, 0, stream>>>(v0, v1, v2, start, dur, ws, out);
}